// Round 1
// 1269.519 us; speedup vs baseline: 1.2817x; 1.2817x over previous
//
#include <hip/hip_runtime.h>
#include <stdint.h>

#define IN_F   4096
#define OUT_F  11008
#define GS     128
#define M_TOT  8192   // BATCH*SEQ = 4*2048

typedef __attribute__((ext_vector_type(8))) short          short8;
typedef __attribute__((ext_vector_type(8))) unsigned short ushort8;
typedef __attribute__((ext_vector_type(4))) float          f32x4;

// round-to-nearest-even fp32 -> bf16
static __device__ __forceinline__ unsigned short f2bf(float f) {
    union { float f; uint32_t u; } v; v.f = f;
    return (unsigned short)((v.u + 0x7FFFu + ((v.u >> 16) & 1u)) >> 16);
}

// ---------------- 1: x fp32 -> bf16 ----------------
__global__ __launch_bounds__(256) void convert_x(const float* __restrict__ x,
                                                 unsigned short* __restrict__ xb) {
    int tid = blockIdx.x * 256 + threadIdx.x;   // one thread = 8 elements
    const float4* xp = ((const float4*)x) + (size_t)tid * 2;
    float4 a = xp[0], b = xp[1];
    ushort8 o;
    o[0] = f2bf(a.x); o[1] = f2bf(a.y); o[2] = f2bf(a.z); o[3] = f2bf(a.w);
    o[4] = f2bf(b.x); o[5] = f2bf(b.y); o[6] = f2bf(b.z); o[7] = f2bf(b.w);
    ((ushort8*)xb)[tid] = o;
}

// ---------------- 2: dequant to W^T bf16 [N, K], coalesced via LDS transpose --------
// Tile: 64 n  x  32 k8 (256 k elems). Reads n-fast (coalesced); writes W^T rows
// k-contiguous (coalesced). LDS [64][264]: row stride 33 x 16B (odd) => <=2-way
// bank aliasing (free), and 16B-aligned rows.
__global__ __launch_bounds__(256) void dequant_w(const int*   __restrict__ qw,
                                                 const int*   __restrict__ qz,
                                                 const float* __restrict__ sc,
                                                 unsigned short* __restrict__ wt) {
    __shared__ unsigned short lt[64][264];
    const int t   = threadIdx.x;
    const int nb  = blockIdx.x * 64;      // 172 blocks
    const int k80 = blockIdx.y * 32;      // 16 blocks
    const int n_l = t & 63;
    const int kq  = t >> 6;               // 0..3
    const int n   = nb + n_l;
#pragma unroll
    for (int r = 0; r < 8; ++r) {
        const int k8l = kq * 8 + r;       // 0..31
        const int k8  = k80 + k8l;
        const int g   = k8 >> 4;
        const int q   = qw[(size_t)k8 * OUT_F + n];
        const int zq  = qz[(size_t)g * (OUT_F / 8) + (n >> 3)];
        const int z   = ((zq >> ((n & 7) * 4)) & 0xF) + 1;
        const float s = sc[(size_t)g * OUT_F + n];
        ushort8 o;
#pragma unroll
        for (int j = 0; j < 8; ++j)
            o[j] = f2bf((float)(((q >> (4 * j)) & 0xF) - z) * s);
        *(ushort8*)&lt[n_l][k8l * 8] = o;
    }
    __syncthreads();
    const int c = t & 31, r0 = t >> 5;
#pragma unroll
    for (int p = 0; p < 8; ++p) {
        const int row = p * 8 + r0;
        *(ushort8*)&wt[(size_t)(nb + row) * IN_F + k80 * 8 + c * 8] =
            *(const ushort8*)&lt[row][c * 8];
    }
}

// ---------------- 3: bf16 GEMM, 256x256 tile, 8-phase counted-vmcnt (m201 template) --
// 8 waves (2M x 4N), per-wave C = 128x64 (M interleave: frag F at row wm*16+F*32;
// N interleave: frag G at col wn*16+G*64). BK=64, 2 K-tiles per iteration.
// LDS: 2 dbuf x [256][64] bf16 for A and B = 128 KiB, XOR-swizzled
// byte ^= ((row&7)<<4): uniform 8-access/bank on ds_read_b128 (minimum), and a
// 16B-chunk involution => linear global_load_lds dest + pre-swizzled global src.
// Schedule (derived from the m201 recipe, issue-after-last-read proof):
//   quadrants per K-tile: (0,0),(0,1),(1,1),(1,0); region last-read phases:
//   Ah0=p1, Bh1=p2, Ah1=p3, Bh0=p4 => stage issues Ah0@p+1,Bh1@p+2,Ah1@p+3,Bh0@p+4.
//   vmcnt(6) at phases 4 and 8 only (3 half-tiles = 6 loads in flight).
#define NWG 1376  // (8192/256)*(11008/256) = 32*43, divisible by 8

#define GLL(SRC, DST) __builtin_amdgcn_global_load_lds(                        \
    (const __attribute__((address_space(1))) void*)(SRC),                      \
    (__attribute__((address_space(3))) void*)(DST), 16, 0, 0)

#define STAGE_A(B_, H_, KT_) do { _Pragma("unroll")                            \
    for (int j_ = 0; j_ < 2; ++j_)                                             \
        GLL(Aptr + (size_t)(m0 + (H_) * 128 + j_ * 64 + srow) * IN_F +         \
                (KT_) * 64 + scol,                                             \
            &lA[B_][(H_) * 8192 + j_ * 4096 + wv * 512]); } while (0)

#define STAGE_B(B_, H_, KT_) do { _Pragma("unroll")                            \
    for (int j_ = 0; j_ < 2; ++j_)                                             \
        GLL(Bptr + (size_t)(n0 + (H_) * 128 + j_ * 64 + srow) * IN_F +         \
                (KT_) * 64 + scol,                                             \
            &lB[B_][(H_) * 8192 + j_ * 4096 + wv * 512]); } while (0)

#define RDA(B_, I_) do { _Pragma("unroll")                                     \
    for (int f_ = 0; f_ < 4; ++f_) {                                           \
        aF[f_][0] = *(const short8*)(lAp[B_] + abase + ((I_) * 4 + f_) * 4096 + cs0); \
        aF[f_][1] = *(const short8*)(lAp[B_] + abase + ((I_) * 4 + f_) * 4096 + cs1); \
    } } while (0)

#define RDB(DST, B_, J_) do { _Pragma("unroll")                                \
    for (int g_ = 0; g_ < 2; ++g_) {                                           \
        DST[g_][0] = *(const short8*)(lBp[B_] + bbase + ((J_) * 2 + g_) * 8192 + cs0); \
        DST[g_][1] = *(const short8*)(lBp[B_] + bbase + ((J_) * 2 + g_) * 8192 + cs1); \
    } } while (0)

#define MM(BF, I_, J_) do { _Pragma("unroll")                                  \
    for (int f_ = 0; f_ < 4; ++f_) { _Pragma("unroll")                         \
        for (int g_ = 0; g_ < 2; ++g_) { _Pragma("unroll")                     \
            for (int s_ = 0; s_ < 2; ++s_) {                                   \
                acc[(I_) * 4 + f_][(J_) * 2 + g_] =                            \
                    __builtin_amdgcn_mfma_f32_16x16x32_bf16(                   \
                        aF[f_][s_], (BF)[g_][s_],                              \
                        acc[(I_) * 4 + f_][(J_) * 2 + g_], 0, 0, 0);           \
    } } } } while (0)

#define MMP(BF, I_, J_) do { __builtin_amdgcn_s_setprio(1); MM(BF, I_, J_);    \
    __builtin_amdgcn_s_setprio(0); } while (0)

#define BARR() do { __builtin_amdgcn_sched_barrier(0);                         \
    __builtin_amdgcn_s_barrier(); __builtin_amdgcn_sched_barrier(0); } while (0)

#define VM6() asm volatile("s_waitcnt vmcnt(6)" ::: "memory")

__global__ __launch_bounds__(512) void gemm8p(const unsigned short* __restrict__ Aptr,
                                              const unsigned short* __restrict__ Bptr,
                                              float* __restrict__ C) {
    __shared__ unsigned short lA[2][16384];   // 2 x [256][64] bf16 = 64 KiB
    __shared__ unsigned short lB[2][16384];   // 64 KiB

    const int tid = threadIdx.x;
    const int l   = tid & 63;
    const int wv  = tid >> 6;      // 0..7
    const int wm  = wv & 1;        // 2 waves in M
    const int wn  = wv >> 1;       // 4 waves in N
    const int fr  = l & 15;        // fragment row
    const int c0  = l >> 4;        // 16B chunk within 32-k window
    const int x7  = l & 7;         // row&7 of this lane's reads (rows are 16-aligned)

    // swizzled read column offsets (bytes): slot = (s*4 | c0) ^ (row&7)
    const int cs0 = (c0 ^ x7) << 4;
    const int cs1 = ((4 | c0) ^ x7) << 4;
    const int abase = (wm * 16 + fr) * 128;
    const int bbase = (wn * 16 + fr) * 128;

    // staging: linear LDS dest (base + lane*16); pre-swizzle the global source
    const int srow = wv * 8 + (l >> 3);
    const int scol = (x7 ^ ((l >> 3) & 7)) * 8;   // elements

    // bijective XCD swizzle (NWG % 8 == 0)
    const int bid = blockIdx.x;
    const int swz = (bid & 7) * (NWG / 8) + (bid >> 3);
    const int m0 = (swz & 31) * 256;
    const int n0 = (swz >> 5) * 256;

    const char* const lAp[2] = {(const char*)&lA[0][0], (const char*)&lA[1][0]};
    const char* const lBp[2] = {(const char*)&lB[0][0], (const char*)&lB[1][0]};

    f32x4 acc[8][4] = {};
    short8 aF[4][2], b0[2][2], b1[2][2];

    // prologue: tile0 (all 4 half-tiles) + tile1 (Ah0,Bh1,Ah1); Bh0_t1 comes in P1.
    STAGE_A(0, 0, 0); STAGE_B(0, 1, 0); STAGE_A(0, 1, 0); STAGE_B(0, 0, 0);
    STAGE_A(1, 0, 1); STAGE_B(1, 1, 1); STAGE_A(1, 1, 1);
    VM6(); BARR();    // tile0 fully landed; 3 half-tiles of tile1 in flight

    for (int it = 0; it < 32; ++it) {
        const int t   = 2 * it;
        const int ktA = (t + 2) & 63;   // wraps harmlessly on last iteration
        const int ktB = (t + 3) & 63;
        // P1: quad (0,0) of t [buf0]; stage (t+1, Bh0) -> buf1
        RDA(0, 0); RDB(b0, 0, 0); STAGE_B(1, 0, t + 1);
        BARR(); MMP(b0, 0, 0); BARR();
        // P2: quad (0,1); stage (t+2, Ah0) -> buf0 (Ah0 last read in P1)
        RDB(b1, 0, 1); STAGE_A(0, 0, ktA);
        BARR(); MMP(b1, 0, 1); BARR();
        // P3: quad (1,1); stage (t+2, Bh1) -> buf0 (Bh1 last read in P2)
        RDA(0, 1); STAGE_B(0, 1, ktA);
        BARR(); MMP(b1, 1, 1); BARR();
        // P4: quad (1,0); stage (t+2, Ah1) -> buf0 (Ah1 last read in P3)
        RDB(b0, 0, 0); STAGE_A(0, 1, ktA);
        BARR(); MMP(b0, 1, 0); VM6(); BARR();   // (t+1,Bh0) landed for P5
        // P5: quad (0,0) of t+1 [buf1]; stage (t+2, Bh0) -> buf0 (Bh0 last read in P4)
        RDA(1, 0); RDB(b0, 1, 0); STAGE_B(0, 0, ktA);
        BARR(); MMP(b0, 0, 0); BARR();
        // P6: quad (0,1); stage (t+3, Ah0) -> buf1
        RDB(b1, 1, 1); STAGE_A(1, 0, ktB);
        BARR(); MMP(b1, 0, 1); BARR();
        // P7: quad (1,1); stage (t+3, Bh1) -> buf1
        RDA(1, 1); STAGE_B(1, 1, ktB);
        BARR(); MMP(b1, 1, 1); BARR();
        // P8: quad (1,0); stage (t+3, Ah1) -> buf1
        RDB(b0, 1, 0); STAGE_A(1, 1, ktB);
        BARR(); MMP(b0, 1, 0); VM6(); BARR();   // (t+2,Bh0) landed for next P1
    }

    // epilogue: C/D layout col=lane&15, row=(lane>>4)*4+r  [measured m89]
    const int col = fr, row4 = c0 * 4;
#pragma unroll
    for (int f = 0; f < 8; ++f)
#pragma unroll
        for (int g = 0; g < 4; ++g)
#pragma unroll
            for (int r = 0; r < 4; ++r)
                C[(size_t)(m0 + wm * 16 + f * 32 + row4 + r) * OUT_F +
                  (n0 + wn * 16 + g * 64 + col)] = acc[f][g][r];
}

// ---------------- fallback (only if ws too small): fused naive fp32 ----------------
__global__ __launch_bounds__(256) void fallback_k(const float* __restrict__ x,
                                                  const int*   __restrict__ qw,
                                                  const int*   __restrict__ qz,
                                                  const float* __restrict__ sc,
                                                  float* __restrict__ out) {
    size_t tid = (size_t)blockIdx.x * 256 + threadIdx.x;
    if (tid >= (size_t)M_TOT * OUT_F) return;
    int n = (int)(tid % OUT_F);
    size_t m = tid / OUT_F;
    float acc = 0.f;
    for (int k8 = 0; k8 < IN_F / 8; ++k8) {
        int q = qw[(size_t)k8 * OUT_F + n];
        int g = k8 >> 4;
        int z = ((qz[(size_t)g * (OUT_F / 8) + (n >> 3)] >> ((n & 7) * 4)) & 0xF) + 1;
        float s = sc[(size_t)g * OUT_F + n];
#pragma unroll
        for (int j = 0; j < 8; ++j) {
            float w = (float)(((q >> (4 * j)) & 0xF) - z) * s;
            acc += x[m * IN_F + k8 * 8 + j] * w;
        }
    }
    out[tid] = acc;
}

extern "C" void kernel_launch(void* const* d_in, const int* in_sizes, int n_in,
                              void* d_out, int out_size, void* d_ws, size_t ws_size,
                              hipStream_t stream) {
    const float* x  = (const float*)d_in[0];
    const int*   qw = (const int*)d_in[1];
    const int*   qz = (const int*)d_in[2];
    const float* sc = (const float*)d_in[3];
    float* out = (float*)d_out;

    const size_t needA = (size_t)M_TOT * IN_F * 2;   // 67 MB bf16 x
    const size_t needB = (size_t)OUT_F * IN_F * 2;   // 90 MB bf16 W^T

    if (ws_size >= needA + needB) {
        unsigned short* xb = (unsigned short*)d_ws;
        unsigned short* wt = (unsigned short*)((char*)d_ws + needA);
        hipLaunchKernelGGL(convert_x, dim3(M_TOT * (IN_F / 8) / 256), dim3(256), 0, stream, x, xb);
        hipLaunchKernelGGL(dequant_w, dim3(OUT_F / 64, IN_F / 8 / 32), dim3(256), 0, stream,
                           qw, qz, sc, wt);
        hipLaunchKernelGGL(gemm8p, dim3(NWG), dim3(512), 0, stream, xb, wt, out);
    } else {
        size_t total = (size_t)M_TOT * OUT_F;
        hipLaunchKernelGGL(fallback_k, dim3((unsigned)((total + 255) / 256)), dim3(256), 0, stream,
                           x, qw, qz, sc, out);
    }
}

// Round 2
// 1194.443 us; speedup vs baseline: 1.3623x; 1.0629x over previous
//
#include <hip/hip_runtime.h>
#include <stdint.h>

#define IN_F   4096
#define OUT_F  11008
#define GS     128
#define M_TOT  8192   // BATCH*SEQ = 4*2048

typedef __attribute__((ext_vector_type(8))) short          short8;
typedef __attribute__((ext_vector_type(8))) unsigned short ushort8;
typedef __attribute__((ext_vector_type(4))) float          f32x4;

// round-to-nearest-even fp32 -> bf16
static __device__ __forceinline__ unsigned short f2bf(float f) {
    union { float f; uint32_t u; } v; v.f = f;
    return (unsigned short)((v.u + 0x7FFFu + ((v.u >> 16) & 1u)) >> 16);
}

// ---------------- 1: x fp32 -> bf16 ----------------
__global__ __launch_bounds__(256) void convert_x(const float* __restrict__ x,
                                                 unsigned short* __restrict__ xb) {
    int tid = blockIdx.x * 256 + threadIdx.x;   // one thread = 8 elements
    const float4* xp = ((const float4*)x) + (size_t)tid * 2;
    float4 a = xp[0], b = xp[1];
    ushort8 o;
    o[0] = f2bf(a.x); o[1] = f2bf(a.y); o[2] = f2bf(a.z); o[3] = f2bf(a.w);
    o[4] = f2bf(b.x); o[5] = f2bf(b.y); o[6] = f2bf(b.z); o[7] = f2bf(b.w);
    ((ushort8*)xb)[tid] = o;
}

// ---------------- 2: dequant to W^T bf16 [N, K], coalesced via LDS transpose --------
__global__ __launch_bounds__(256) void dequant_w(const int*   __restrict__ qw,
                                                 const int*   __restrict__ qz,
                                                 const float* __restrict__ sc,
                                                 unsigned short* __restrict__ wt) {
    __shared__ unsigned short lt[64][264];
    const int t   = threadIdx.x;
    const int nb  = blockIdx.x * 64;      // 172 blocks
    const int k80 = blockIdx.y * 32;      // 16 blocks
    const int n_l = t & 63;
    const int kq  = t >> 6;               // 0..3
    const int n   = nb + n_l;
#pragma unroll
    for (int r = 0; r < 8; ++r) {
        const int k8l = kq * 8 + r;       // 0..31
        const int k8  = k80 + k8l;
        const int g   = k8 >> 4;
        const int q   = qw[(size_t)k8 * OUT_F + n];
        const int zq  = qz[(size_t)g * (OUT_F / 8) + (n >> 3)];
        const int z   = ((zq >> ((n & 7) * 4)) & 0xF) + 1;
        const float s = sc[(size_t)g * OUT_F + n];
        ushort8 o;
#pragma unroll
        for (int j = 0; j < 8; ++j)
            o[j] = f2bf((float)(((q >> (4 * j)) & 0xF) - z) * s);
        *(ushort8*)&lt[n_l][k8l * 8] = o;
    }
    __syncthreads();
    const int c = t & 31, r0 = t >> 5;
#pragma unroll
    for (int p = 0; p < 8; ++p) {
        const int row = p * 8 + r0;
        *(ushort8*)&wt[(size_t)(nb + row) * IN_F + k80 * 8 + c * 8] =
            *(const ushort8*)&lt[row][c * 8];
    }
}

// ---------------- 3: bf16 GEMM, 256x256 tile, 8-phase counted-vmcnt (m201 template) --
// Identical schedule to R1 (verified race-free, 0 bank conflicts). Only change:
// 2D XCD-affine tile mapping. Each XCD owns 4 m-tiles permanently (A slices stay
// L2-hot: 4 panels vs 32 before) and sweeps n in 8-wide rects, so the ~32
// co-resident blocks per XCD form a 4m x 8n rectangle: hot k-slices
// (4+8) x 32 KB << 4 MiB L2. Attacks the vmcnt-stall latency (MfmaUtil 35%,
// VALUBusy 12%, HBM 27% => latency-bound; pipeline depth fixed at 3 phases).
#define NWG 1376  // (8192/256)*(11008/256) = 32*43, divisible by 8

#define GLL(SRC, DST) __builtin_amdgcn_global_load_lds(                        \
    (const __attribute__((address_space(1))) void*)(SRC),                      \
    (__attribute__((address_space(3))) void*)(DST), 16, 0, 0)

#define STAGE_A(B_, H_, KT_) do { _Pragma("unroll")                            \
    for (int j_ = 0; j_ < 2; ++j_)                                             \
        GLL(Aptr + (size_t)(m0 + (H_) * 128 + j_ * 64 + srow) * IN_F +         \
                (KT_) * 64 + scol,                                             \
            &lA[B_][(H_) * 8192 + j_ * 4096 + wv * 512]); } while (0)

#define STAGE_B(B_, H_, KT_) do { _Pragma("unroll")                            \
    for (int j_ = 0; j_ < 2; ++j_)                                             \
        GLL(Bptr + (size_t)(n0 + (H_) * 128 + j_ * 64 + srow) * IN_F +         \
                (KT_) * 64 + scol,                                             \
            &lB[B_][(H_) * 8192 + j_ * 4096 + wv * 512]); } while (0)

#define RDA(B_, I_) do { _Pragma("unroll")                                     \
    for (int f_ = 0; f_ < 4; ++f_) {                                           \
        aF[f_][0] = *(const short8*)(lAp[B_] + abase + ((I_) * 4 + f_) * 4096 + cs0); \
        aF[f_][1] = *(const short8*)(lAp[B_] + abase + ((I_) * 4 + f_) * 4096 + cs1); \
    } } while (0)

#define RDB(DST, B_, J_) do { _Pragma("unroll")                                \
    for (int g_ = 0; g_ < 2; ++g_) {                                           \
        DST[g_][0] = *(const short8*)(lBp[B_] + bbase + ((J_) * 2 + g_) * 8192 + cs0); \
        DST[g_][1] = *(const short8*)(lBp[B_] + bbase + ((J_) * 2 + g_) * 8192 + cs1); \
    } } while (0)

#define MM(BF, I_, J_) do { _Pragma("unroll")                                  \
    for (int f_ = 0; f_ < 4; ++f_) { _Pragma("unroll")                         \
        for (int g_ = 0; g_ < 2; ++g_) { _Pragma("unroll")                     \
            for (int s_ = 0; s_ < 2; ++s_) {                                   \
                acc[(I_) * 4 + f_][(J_) * 2 + g_] =                            \
                    __builtin_amdgcn_mfma_f32_16x16x32_bf16(                   \
                        aF[f_][s_], (BF)[g_][s_],                              \
                        acc[(I_) * 4 + f_][(J_) * 2 + g_], 0, 0, 0);           \
    } } } } while (0)

#define MMP(BF, I_, J_) do { __builtin_amdgcn_s_setprio(1); MM(BF, I_, J_);    \
    __builtin_amdgcn_s_setprio(0); } while (0)

#define BARR() do { __builtin_amdgcn_sched_barrier(0);                         \
    __builtin_amdgcn_s_barrier(); __builtin_amdgcn_sched_barrier(0); } while (0)

#define VM6() asm volatile("s_waitcnt vmcnt(6)" ::: "memory")

__global__ __launch_bounds__(512) void gemm8p(const unsigned short* __restrict__ Aptr,
                                              const unsigned short* __restrict__ Bptr,
                                              float* __restrict__ C) {
    __shared__ unsigned short lA[2][16384];   // 2 x [256][64] bf16 = 64 KiB
    __shared__ unsigned short lB[2][16384];   // 64 KiB

    const int tid = threadIdx.x;
    const int l   = tid & 63;
    const int wv  = tid >> 6;      // 0..7
    const int wm  = wv & 1;        // 2 waves in M
    const int wn  = wv >> 1;       // 4 waves in N
    const int fr  = l & 15;        // fragment row
    const int c0  = l >> 4;        // 16B chunk within 32-k window
    const int x7  = l & 7;         // row&7 of this lane's reads (rows are 16-aligned)

    // swizzled read column offsets (bytes): slot = (s*4 | c0) ^ (row&7)
    const int cs0 = (c0 ^ x7) << 4;
    const int cs1 = ((4 | c0) ^ x7) << 4;
    const int abase = (wm * 16 + fr) * 128;
    const int bbase = (wn * 16 + fr) * 128;

    // staging: linear LDS dest (base + lane*16); pre-swizzle the global source
    const int srow = wv * 8 + (l >> 3);
    const int scol = (x7 ^ ((l >> 3) & 7)) * 8;   // elements

    // --- 2D XCD-affine tile map (bijective over 32m x 43n; hand-verified) ---
    // xcd = bid&7 (round-robin dispatch); j = bid>>3 in [0,172).
    // j<160: rect r=j>>5 (5 full 4x8 rects), p=j&31 -> mt=4*xcd+(p&3), nt=8r+(p>>2)
    // j>=160: ragged 4x3 rect -> nt = 40 + (p>>2)
    const int bid = blockIdx.x;
    const int xcd = bid & 7;
    const int j   = bid >> 3;
    int mt, nt;
    if (j < 160) { const int r = j >> 5, p = j & 31; mt = xcd * 4 + (p & 3); nt = r * 8 + (p >> 2); }
    else         { const int p = j - 160;            mt = xcd * 4 + (p & 3); nt = 40 + (p >> 2); }
    const int m0 = mt * 256;
    const int n0 = nt * 256;

    const char* const lAp[2] = {(const char*)&lA[0][0], (const char*)&lA[1][0]};
    const char* const lBp[2] = {(const char*)&lB[0][0], (const char*)&lB[1][0]};

    f32x4 acc[8][4] = {};
    short8 aF[4][2], b0[2][2], b1[2][2];

    // prologue: tile0 (all 4 half-tiles) + tile1 (Ah0,Bh1,Ah1); Bh0_t1 comes in P1.
    STAGE_A(0, 0, 0); STAGE_B(0, 1, 0); STAGE_A(0, 1, 0); STAGE_B(0, 0, 0);
    STAGE_A(1, 0, 1); STAGE_B(1, 1, 1); STAGE_A(1, 1, 1);
    VM6(); BARR();    // tile0 fully landed; 3 half-tiles of tile1 in flight

    for (int it = 0; it < 32; ++it) {
        const int t   = 2 * it;
        const int ktA = (t + 2) & 63;   // wraps harmlessly on last iteration
        const int ktB = (t + 3) & 63;
        // P1: quad (0,0) of t [buf0]; stage (t+1, Bh0) -> buf1
        RDA(0, 0); RDB(b0, 0, 0); STAGE_B(1, 0, t + 1);
        BARR(); MMP(b0, 0, 0); BARR();
        // P2: quad (0,1); stage (t+2, Ah0) -> buf0 (Ah0 last read in P1)
        RDB(b1, 0, 1); STAGE_A(0, 0, ktA);
        BARR(); MMP(b1, 0, 1); BARR();
        // P3: quad (1,1); stage (t+2, Bh1) -> buf0 (Bh1 last read in P2)
        RDA(0, 1); STAGE_B(0, 1, ktA);
        BARR(); MMP(b1, 1, 1); BARR();
        // P4: quad (1,0); stage (t+2, Ah1) -> buf0 (Ah1 last read in P3)
        RDB(b0, 0, 0); STAGE_A(0, 1, ktA);
        BARR(); MMP(b0, 1, 0); VM6(); BARR();   // (t+1,Bh0) landed for P5
        // P5: quad (0,0) of t+1 [buf1]; stage (t+2, Bh0) -> buf0 (Bh0 last read in P4)
        RDA(1, 0); RDB(b0, 1, 0); STAGE_B(0, 0, ktA);
        BARR(); MMP(b0, 0, 0); BARR();
        // P6: quad (0,1); stage (t+3, Ah0) -> buf1
        RDB(b1, 1, 1); STAGE_A(1, 0, ktB);
        BARR(); MMP(b1, 0, 1); BARR();
        // P7: quad (1,1); stage (t+3, Bh1) -> buf1
        RDA(1, 1); STAGE_B(1, 1, ktB);
        BARR(); MMP(b1, 1, 1); BARR();
        // P8: quad (1,0); stage (t+3, Ah1) -> buf1
        RDB(b0, 1, 0); STAGE_A(1, 1, ktB);
        BARR(); MMP(b0, 1, 0); VM6(); BARR();   // (t+2,Bh0) landed for next P1
    }

    // epilogue: C/D layout col=lane&15, row=(lane>>4)*4+r  [measured m89]
    const int col = fr, row4 = c0 * 4;
#pragma unroll
    for (int f = 0; f < 8; ++f)
#pragma unroll
        for (int g = 0; g < 4; ++g)
#pragma unroll
            for (int r = 0; r < 4; ++r)
                C[(size_t)(m0 + wm * 16 + f * 32 + row4 + r) * OUT_F +
                  (n0 + wn * 16 + g * 64 + col)] = acc[f][g][r];
}

// ---------------- fallback (only if ws too small): fused naive fp32 ----------------
__global__ __launch_bounds__(256) void fallback_k(const float* __restrict__ x,
                                                  const int*   __restrict__ qw,
                                                  const int*   __restrict__ qz,
                                                  const float* __restrict__ sc,
                                                  float* __restrict__ out) {
    size_t tid = (size_t)blockIdx.x * 256 + threadIdx.x;
    if (tid >= (size_t)M_TOT * OUT_F) return;
    int n = (int)(tid % OUT_F);
    size_t m = tid / OUT_F;
    float acc = 0.f;
    for (int k8 = 0; k8 < IN_F / 8; ++k8) {
        int q = qw[(size_t)k8 * OUT_F + n];
        int g = k8 >> 4;
        int z = ((qz[(size_t)g * (OUT_F / 8) + (n >> 3)] >> ((n & 7) * 4)) & 0xF) + 1;
        float s = sc[(size_t)g * OUT_F + n];
#pragma unroll
        for (int j = 0; j < 8; ++j) {
            float w = (float)(((q >> (4 * j)) & 0xF) - z) * s;
            acc += x[m * IN_F + k8 * 8 + j] * w;
        }
    }
    out[tid] = acc;
}

extern "C" void kernel_launch(void* const* d_in, const int* in_sizes, int n_in,
                              void* d_out, int out_size, void* d_ws, size_t ws_size,
                              hipStream_t stream) {
    const float* x  = (const float*)d_in[0];
    const int*   qw = (const int*)d_in[1];
    const int*   qz = (const int*)d_in[2];
    const float* sc = (const float*)d_in[3];
    float* out = (float*)d_out;

    const size_t needA = (size_t)M_TOT * IN_F * 2;   // 67 MB bf16 x
    const size_t needB = (size_t)OUT_F * IN_F * 2;   // 90 MB bf16 W^T

    if (ws_size >= needA + needB) {
        unsigned short* xb = (unsigned short*)d_ws;
        unsigned short* wt = (unsigned short*)((char*)d_ws + needA);
        hipLaunchKernelGGL(convert_x, dim3(M_TOT * (IN_F / 8) / 256), dim3(256), 0, stream, x, xb);
        hipLaunchKernelGGL(dequant_w, dim3(OUT_F / 64, IN_F / 8 / 32), dim3(256), 0, stream,
                           qw, qz, sc, wt);
        hipLaunchKernelGGL(gemm8p, dim3(NWG), dim3(512), 0, stream, xb, wt, out);
    } else {
        size_t total = (size_t)M_TOT * OUT_F;
        hipLaunchKernelGGL(fallback_k, dim3((unsigned)((total + 255) / 256)), dim3(256), 0, stream,
                           x, qw, qz, sc, out);
    }
}

// Round 3
// 1110.592 us; speedup vs baseline: 1.4651x; 1.0755x over previous
//
#include <hip/hip_runtime.h>
#include <stdint.h>

#define IN_F   4096
#define OUT_F  11008
#define GS     128
#define M_TOT  8192   // BATCH*SEQ = 4*2048

typedef __attribute__((ext_vector_type(8))) short          short8;
typedef __attribute__((ext_vector_type(8))) unsigned short ushort8;
typedef __attribute__((ext_vector_type(4))) float          f32x4;

// round-to-nearest-even fp32 -> bf16
static __device__ __forceinline__ unsigned short f2bf(float f) {
    union { float f; uint32_t u; } v; v.f = f;
    return (unsigned short)((v.u + 0x7FFFu + ((v.u >> 16) & 1u)) >> 16);
}

// ---------------- 1: x fp32 -> bf16 ----------------
__global__ __launch_bounds__(256) void convert_x(const float* __restrict__ x,
                                                 unsigned short* __restrict__ xb) {
    int tid = blockIdx.x * 256 + threadIdx.x;   // one thread = 8 elements
    const float4* xp = ((const float4*)x) + (size_t)tid * 2;
    float4 a = xp[0], b = xp[1];
    ushort8 o;
    o[0] = f2bf(a.x); o[1] = f2bf(a.y); o[2] = f2bf(a.z); o[3] = f2bf(a.w);
    o[4] = f2bf(b.x); o[5] = f2bf(b.y); o[6] = f2bf(b.z); o[7] = f2bf(b.w);
    ((ushort8*)xb)[tid] = o;
}

// ---------------- 2: dequant to W^T bf16 [N, K], coalesced via LDS transpose --------
__global__ __launch_bounds__(256) void dequant_w(const int*   __restrict__ qw,
                                                 const int*   __restrict__ qz,
                                                 const float* __restrict__ sc,
                                                 unsigned short* __restrict__ wt) {
    __shared__ unsigned short lt[64][264];
    const int t   = threadIdx.x;
    const int nb  = blockIdx.x * 64;      // 172 blocks
    const int k80 = blockIdx.y * 32;      // 16 blocks
    const int n_l = t & 63;
    const int kq  = t >> 6;               // 0..3
    const int n   = nb + n_l;
#pragma unroll
    for (int r = 0; r < 8; ++r) {
        const int k8l = kq * 8 + r;       // 0..31
        const int k8  = k80 + k8l;
        const int g   = k8 >> 4;
        const int q   = qw[(size_t)k8 * OUT_F + n];
        const int zq  = qz[(size_t)g * (OUT_F / 8) + (n >> 3)];
        const int z   = ((zq >> ((n & 7) * 4)) & 0xF) + 1;
        const float s = sc[(size_t)g * OUT_F + n];
        ushort8 o;
#pragma unroll
        for (int j = 0; j < 8; ++j)
            o[j] = f2bf((float)(((q >> (4 * j)) & 0xF) - z) * s);
        *(ushort8*)&lt[n_l][k8l * 8] = o;
    }
    __syncthreads();
    const int c = t & 31, r0 = t >> 5;
#pragma unroll
    for (int p = 0; p < 8; ++p) {
        const int row = p * 8 + r0;
        *(ushort8*)&wt[(size_t)(nb + row) * IN_F + k80 * 8 + c * 8] =
            *(const ushort8*)&lt[row][c * 8];
    }
}

// ---------------- 3: bf16 GEMM, 256x256 tile, 8-phase counted-vmcnt (m201 template) --
// R3 changes vs R2 (schedule/sync structure otherwise identical, race proof unchanged):
//  (a) UN-PIN: BARR is now a raw s_barrier (m201 template form). The R2 version
//      wrapped every barrier in sched_barrier(0) -- m141's measured 1.7x mistake.
//      C++ ds_reads get exact compiler lgkmcnt; no manual pin needed.
//  (b) Drop redundant RDB in P4/P8: b0 still holds quadrant J0 from P1/P5.
//      -14% LDS-read traffic (the structural ceiling of this template).
#define NWG 1376  // (8192/256)*(11008/256) = 32*43, divisible by 8

#define GLL(SRC, DST) __builtin_amdgcn_global_load_lds(                        \
    (const __attribute__((address_space(1))) void*)(SRC),                      \
    (__attribute__((address_space(3))) void*)(DST), 16, 0, 0)

#define STAGE_A(B_, H_, KT_) do { _Pragma("unroll")                            \
    for (int j_ = 0; j_ < 2; ++j_)                                             \
        GLL(Aptr + (size_t)(m0 + (H_) * 128 + j_ * 64 + srow) * IN_F +         \
                (KT_) * 64 + scol,                                             \
            &lA[B_][(H_) * 8192 + j_ * 4096 + wv * 512]); } while (0)

#define STAGE_B(B_, H_, KT_) do { _Pragma("unroll")                            \
    for (int j_ = 0; j_ < 2; ++j_)                                             \
        GLL(Bptr + (size_t)(n0 + (H_) * 128 + j_ * 64 + srow) * IN_F +         \
                (KT_) * 64 + scol,                                             \
            &lB[B_][(H_) * 8192 + j_ * 4096 + wv * 512]); } while (0)

#define RDA(B_, I_) do { _Pragma("unroll")                                     \
    for (int f_ = 0; f_ < 4; ++f_) {                                           \
        aF[f_][0] = *(const short8*)(lAp[B_] + abase + ((I_) * 4 + f_) * 4096 + cs0); \
        aF[f_][1] = *(const short8*)(lAp[B_] + abase + ((I_) * 4 + f_) * 4096 + cs1); \
    } } while (0)

#define RDB(DST, B_, J_) do { _Pragma("unroll")                                \
    for (int g_ = 0; g_ < 2; ++g_) {                                           \
        DST[g_][0] = *(const short8*)(lBp[B_] + bbase + ((J_) * 2 + g_) * 8192 + cs0); \
        DST[g_][1] = *(const short8*)(lBp[B_] + bbase + ((J_) * 2 + g_) * 8192 + cs1); \
    } } while (0)

#define MM(BF, I_, J_) do { _Pragma("unroll")                                  \
    for (int f_ = 0; f_ < 4; ++f_) { _Pragma("unroll")                         \
        for (int g_ = 0; g_ < 2; ++g_) { _Pragma("unroll")                     \
            for (int s_ = 0; s_ < 2; ++s_) {                                   \
                acc[(I_) * 4 + f_][(J_) * 2 + g_] =                            \
                    __builtin_amdgcn_mfma_f32_16x16x32_bf16(                   \
                        aF[f_][s_], (BF)[g_][s_],                              \
                        acc[(I_) * 4 + f_][(J_) * 2 + g_], 0, 0, 0);           \
    } } } } while (0)

#define MMP(BF, I_, J_) do { __builtin_amdgcn_s_setprio(1); MM(BF, I_, J_);    \
    __builtin_amdgcn_s_setprio(0); } while (0)

#define BARR() __builtin_amdgcn_s_barrier()

#define VM6() asm volatile("s_waitcnt vmcnt(6)" ::: "memory")

__global__ __launch_bounds__(512) void gemm8p(const unsigned short* __restrict__ Aptr,
                                              const unsigned short* __restrict__ Bptr,
                                              float* __restrict__ C) {
    __shared__ unsigned short lA[2][16384];   // 2 x [256][64] bf16 = 64 KiB
    __shared__ unsigned short lB[2][16384];   // 64 KiB

    const int tid = threadIdx.x;
    const int l   = tid & 63;
    const int wv  = tid >> 6;      // 0..7
    const int wm  = wv & 1;        // 2 waves in M
    const int wn  = wv >> 1;       // 4 waves in N
    const int fr  = l & 15;        // fragment row
    const int c0  = l >> 4;        // 16B chunk within 32-k window
    const int x7  = l & 7;         // row&7 of this lane's reads (rows are 16-aligned)

    // swizzled read column offsets (bytes): slot = (s*4 | c0) ^ (row&7)
    const int cs0 = (c0 ^ x7) << 4;
    const int cs1 = ((4 | c0) ^ x7) << 4;
    const int abase = (wm * 16 + fr) * 128;
    const int bbase = (wn * 16 + fr) * 128;

    // staging: linear LDS dest (base + lane*16); pre-swizzle the global source
    const int srow = wv * 8 + (l >> 3);
    const int scol = (x7 ^ ((l >> 3) & 7)) * 8;   // elements

    // --- 2D XCD-affine tile map (bijective over 32m x 43n; hand-verified) ---
    const int bid = blockIdx.x;
    const int xcd = bid & 7;
    const int j   = bid >> 3;
    int mt, nt;
    if (j < 160) { const int r = j >> 5, p = j & 31; mt = xcd * 4 + (p & 3); nt = r * 8 + (p >> 2); }
    else         { const int p = j - 160;            mt = xcd * 4 + (p & 3); nt = 40 + (p >> 2); }
    const int m0 = mt * 256;
    const int n0 = nt * 256;

    const char* const lAp[2] = {(const char*)&lA[0][0], (const char*)&lA[1][0]};
    const char* const lBp[2] = {(const char*)&lB[0][0], (const char*)&lB[1][0]};

    f32x4 acc[8][4] = {};
    short8 aF[4][2], b0[2][2], b1[2][2];

    // prologue: tile0 (all 4 half-tiles) + tile1 (Ah0,Bh1,Ah1); Bh0_t1 comes in P1.
    STAGE_A(0, 0, 0); STAGE_B(0, 1, 0); STAGE_A(0, 1, 0); STAGE_B(0, 0, 0);
    STAGE_A(1, 0, 1); STAGE_B(1, 1, 1); STAGE_A(1, 1, 1);
    VM6(); BARR();    // tile0 fully landed; 3 half-tiles of tile1 in flight

    for (int it = 0; it < 32; ++it) {
        const int t   = 2 * it;
        const int ktA = (t + 2) & 63;   // wraps harmlessly on last iteration
        const int ktB = (t + 3) & 63;
        // P1: quad (0,0) of t [buf0]; stage (t+1, Bh0) -> buf1
        RDA(0, 0); RDB(b0, 0, 0); STAGE_B(1, 0, t + 1);
        BARR(); MMP(b0, 0, 0); BARR();
        // P2: quad (0,1); stage (t+2, Ah0) -> buf0 (Ah0 last read in P1)
        RDB(b1, 0, 1); STAGE_A(0, 0, ktA);
        BARR(); MMP(b1, 0, 1); BARR();
        // P3: quad (1,1); stage (t+2, Bh1) -> buf0 (Bh1 last read in P2)
        RDA(0, 1); STAGE_B(0, 1, ktA);
        BARR(); MMP(b1, 1, 1); BARR();
        // P4: quad (1,0) -- b0 still holds J0 from P1 (no re-read); stage (t+2, Ah1)
        STAGE_A(0, 1, ktA);
        BARR(); MMP(b0, 1, 0); VM6(); BARR();   // (t+1,Bh0) landed for P5
        // P5: quad (0,0) of t+1 [buf1]; stage (t+2, Bh0) -> buf0 (Bh0 last read P1)
        RDA(1, 0); RDB(b0, 1, 0); STAGE_B(0, 0, ktA);
        BARR(); MMP(b0, 0, 0); BARR();
        // P6: quad (0,1); stage (t+3, Ah0) -> buf1
        RDB(b1, 1, 1); STAGE_A(1, 0, ktB);
        BARR(); MMP(b1, 0, 1); BARR();
        // P7: quad (1,1); stage (t+3, Bh1) -> buf1
        RDA(1, 1); STAGE_B(1, 1, ktB);
        BARR(); MMP(b1, 1, 1); BARR();
        // P8: quad (1,0) -- b0 still holds J0 from P5 (no re-read); stage (t+3, Ah1)
        STAGE_A(1, 1, ktB);
        BARR(); MMP(b0, 1, 0); VM6(); BARR();   // (t+2,Bh0) landed for next P1
    }

    // epilogue: C/D layout col=lane&15, row=(lane>>4)*4+r  [measured m89]
    const int col = fr, row4 = c0 * 4;
#pragma unroll
    for (int f = 0; f < 8; ++f)
#pragma unroll
        for (int g = 0; g < 4; ++g)
#pragma unroll
            for (int r = 0; r < 4; ++r)
                C[(size_t)(m0 + wm * 16 + f * 32 + row4 + r) * OUT_F +
                  (n0 + wn * 16 + g * 64 + col)] = acc[f][g][r];
}

// ---------------- fallback (only if ws too small): fused naive fp32 ----------------
__global__ __launch_bounds__(256) void fallback_k(const float* __restrict__ x,
                                                  const int*   __restrict__ qw,
                                                  const int*   __restrict__ qz,
                                                  const float* __restrict__ sc,
                                                  float* __restrict__ out) {
    size_t tid = (size_t)blockIdx.x * 256 + threadIdx.x;
    if (tid >= (size_t)M_TOT * OUT_F) return;
    int n = (int)(tid % OUT_F);
    size_t m = tid / OUT_F;
    float acc = 0.f;
    for (int k8 = 0; k8 < IN_F / 8; ++k8) {
        int q = qw[(size_t)k8 * OUT_F + n];
        int g = k8 >> 4;
        int z = ((qz[(size_t)g * (OUT_F / 8) + (n >> 3)] >> ((n & 7) * 4)) & 0xF) + 1;
        float s = sc[(size_t)g * OUT_F + n];
#pragma unroll
        for (int j = 0; j < 8; ++j) {
            float w = (float)(((q >> (4 * j)) & 0xF) - z) * s;
            acc += x[m * IN_F + k8 * 8 + j] * w;
        }
    }
    out[tid] = acc;
}

extern "C" void kernel_launch(void* const* d_in, const int* in_sizes, int n_in,
                              void* d_out, int out_size, void* d_ws, size_t ws_size,
                              hipStream_t stream) {
    const float* x  = (const float*)d_in[0];
    const int*   qw = (const int*)d_in[1];
    const int*   qz = (const int*)d_in[2];
    const float* sc = (const float*)d_in[3];
    float* out = (float*)d_out;

    const size_t needA = (size_t)M_TOT * IN_F * 2;   // 67 MB bf16 x
    const size_t needB = (size_t)OUT_F * IN_F * 2;   // 90 MB bf16 W^T

    if (ws_size >= needA + needB) {
        unsigned short* xb = (unsigned short*)d_ws;
        unsigned short* wt = (unsigned short*)((char*)d_ws + needA);
        hipLaunchKernelGGL(convert_x, dim3(M_TOT * (IN_F / 8) / 256), dim3(256), 0, stream, x, xb);
        hipLaunchKernelGGL(dequant_w, dim3(OUT_F / 64, IN_F / 8 / 32), dim3(256), 0, stream,
                           qw, qz, sc, wt);
        hipLaunchKernelGGL(gemm8p, dim3(NWG), dim3(512), 0, stream, xb, wt, out);
    } else {
        size_t total = (size_t)M_TOT * OUT_F;
        hipLaunchKernelGGL(fallback_k, dim3((unsigned)((total + 255) / 256)), dim3(256), 0, stream,
                           x, qw, qz, sc, out);
    }
}